// Round 1
// 2153.502 us; speedup vs baseline: 1.4254x; 1.4254x over previous
//
#include <hip/hip_runtime.h>

typedef __attribute__((ext_vector_type(8))) short bf16x8;   // 8 bf16 (4 VGPRs)
typedef __attribute__((ext_vector_type(4))) float f32x4;    // MFMA acc

#define NBATCH 64
#define NH     512
#define NV     8001
#define NVP    8064      // padded V (63 tiles of 128)
#define NSTEP  128       // T-1
#define NG     2048      // 4*NH gate columns
#define SLAB   32768     // NBATCH*NH ushorts = one 64KB step-slab

// ---- workspace layout (bytes) ----
// State uses WRITE-ONCE sequence slabs: no address is ever rewritten, so
// consumer L1/L2 can never hold a stale copy -> plain cached loads are safe
// with NO acquire fence. Producers publish via sc1 (agent-scope) stores.
#define OFF_XS    ((size_t)0)
#define SZ_XS     ((size_t)NSTEP*SLAB*2)                 // 8 MB  bf16 [t][b][h]
#define OFF_WP    (OFF_XS + SZ_XS)
#define SZ_WP     ((size_t)2*2048*1024*2)                // 8 MB  frag-packed weights
#define OFF_WDEC  (OFF_WP + SZ_WP)
#define SZ_WDEC   ((size_t)NVP*NH*2)                     // 8.26 MB bf16, zero-padded rows
#define OFF_BIAS  (OFF_WDEC + SZ_WDEC)
#define SZ_BIAS   ((size_t)2*NG*4)                       // combined b_ih+b_hh per layer, fp32
#define OFF_H1    (OFF_BIAS + SZ_BIAS)
#define SZ_H1     ((size_t)(NSTEP+1)*SLAB*2)             // 8.06 MB  h1 after step t -> slot t+1 (slot 0 = zeros)
#define OFF_AB    (OFF_H1 + SZ_H1)
#define SZ_AB     ((size_t)NSTEP*SLAB*2)                 // 8 MB  a (post-BN1*mask1) at step t -> slot t
#define OFF_H2    (OFF_AB + SZ_AB)
#define SZ_H2     ((size_t)(NSTEP+1)*SLAB*2)             // 8.06 MB  h2 slots (slot 0 = zeros)
#define OFF_BSEQ  (OFF_H2 + SZ_H2)
#define SZ_BSEQ   ((size_t)NSTEP*SLAB*2)                 // 8 MB bf16 [t][b][h] (k_dec input)
#define OFF_BAR   (OFF_BSEQ + SZ_BSEQ)
#define SZ_BAR    ((size_t)256*4)                        // per-phase arrival counters

__device__ __forceinline__ unsigned short f2bf(float x) {  // RNE float->bf16
  union { float f; unsigned u; } v; v.f = x;
  unsigned r = v.u + 0x7FFFu + ((v.u >> 16) & 1u);
  return (unsigned short)(r >> 16);
}
__device__ __forceinline__ float sigm(float x) { return 1.f / (1.f + __expf(-x)); }

// ---------------- prep kernels ----------------

// xs[t][b][h] = bf16(emb[x[b][t]][h]), t in [0,128)
__global__ void k_xs(const int* __restrict__ x, const float* __restrict__ emb,
                     unsigned short* __restrict__ xs) {
  int idx = blockIdx.x * 256 + threadIdx.x;          // 128*64*512 threads
  int t = idx >> 15, rem = idx & 32767, b = rem >> 9, h = rem & 511;
  xs[idx] = f2bf(emb[(size_t)x[b * 129 + t] * NH + h]);
}

// wdec[v][h] bf16, zero pad rows v>=8001
__global__ void k_wdec(const float* __restrict__ W, unsigned short* __restrict__ wdec) {
  int idx = blockIdx.x * 256 + threadIdx.x;          // 8064*512 threads
  int v = idx >> 9, h = idx & 511;
  wdec[idx] = (v < NV) ? f2bf(W[(size_t)v * NH + h]) : (unsigned short)0;
}

__global__ void k_bias(const float* __restrict__ bi1, const float* __restrict__ bh1,
                       const float* __restrict__ bi2, const float* __restrict__ bh2,
                       float* __restrict__ bias) {
  int i = blockIdx.x * 256 + threadIdx.x;            // 4096 threads
  bias[i] = (i < NG) ? (bi1[i] + bh1[i]) : (bi2[i - NG] + bh2[i - NG]);
}

// Pack recurrence weights into MFMA B-fragment order.
// Layout: [layer][lb(32)][s(32)][g(4)][lane(64)][8 bf16]; r = g*512+lb*16+(lane&15), k = s*32+(lane>>4)*8
__global__ void k_wpack(const float* __restrict__ Wih1, const float* __restrict__ Whh1,
                        const float* __restrict__ Wih2, const float* __restrict__ Whh2,
                        unsigned short* __restrict__ wp) {
  int tid = blockIdx.x * 256 + threadIdx.x;          // 524288 threads
  int l = tid & 63, g = (tid >> 6) & 3, s = (tid >> 8) & 31, lb = (tid >> 13) & 31, layer = tid >> 18;
  int n = l & 15, q = l >> 4;
  int r = g * NH + lb * 16 + n;
  int k0 = s * 32 + q * 8;
  const float* Wih = layer ? Wih2 : Wih1;
  const float* Whh = layer ? Whh2 : Whh1;
  const float* src = (k0 < NH) ? (Wih + (size_t)r * NH + k0) : (Whh + (size_t)r * NH + (k0 - NH));
  unsigned short tmp[8];
#pragma unroll
  for (int j = 0; j < 8; ++j) tmp[j] = f2bf(src[j]);
  *(uint4*)(wp + (size_t)tid * 8) = *(const uint4*)tmp;
}

// ---------------- cooperative recurrence ----------------
// 64 blocks x 256. Block = (layer = bid>>5, lb = bid&31) owns features [lb*16, lb*16+16).
// Phase p: layer1 computes step t=p (p<128); layer2 computes step t=p-1 (p>=1). 1 barrier/phase.
//
// Coherence protocol (NO per-thread __threadfence, NO L2 invalidation):
//  - h/a outputs are published with agent-scope RELAXED atomic stores (sc1,
//    write-through to the coherence point).
//  - __syncthreads() drains every wave's vmcnt -> all sc1 stores globally visible.
//  - leader does one release fence (covers the tiny dirty set, e.g. bseq) +
//    RELAXED atomicAdd on a write-once per-phase counter, spins RELAXED.
//  - consumers use PLAIN cached loads: state slabs are write-once addresses,
//    so no cache can hold a stale value; a cold miss fetches fresh data from L3.
__global__ void __launch_bounds__(256, 1)
k_recur(const unsigned short* __restrict__ xs, const unsigned short* __restrict__ wpack,
        const float* __restrict__ bias,
        const float* __restrict__ gamma1, const float* __restrict__ beta1, const float* __restrict__ mask1,
        const float* __restrict__ gamma2, const float* __restrict__ beta2, const float* __restrict__ mask2,
        unsigned short* __restrict__ h1q, unsigned short* __restrict__ abq,
        unsigned short* __restrict__ h2q, unsigned short* __restrict__ bseq,
        unsigned* __restrict__ bar) {
  __shared__ unsigned short wlds[32 * 4 * 64 * 8];   // 128 KB: block's weight strip, frag order
  __shared__ float red[4][2][16];                    // BN cross-wave partials

  const int layer = blockIdx.x >> 5, lb = blockIdx.x & 31, f0 = lb * 16;
  const float* gam = layer ? gamma2 : gamma1;
  const float* bet = layer ? beta2 : beta1;
  const float* msk = layer ? mask2 : mask1;
  const float* bias_l = bias + layer * NG;

  { // stage weights -> LDS (contiguous, coalesced)
    const uint4* src = (const uint4*)(wpack + (size_t)blockIdx.x * (32 * 4 * 64 * 8));
    uint4* dst = (uint4*)wlds;
    for (int i = threadIdx.x; i < 32 * 4 * 64; i += 256) dst[i] = src[i];
  }
  __syncthreads();

  const int lane = threadIdx.x & 63, w = threadIdx.x >> 6;
  const int q = lane >> 4, n = lane & 15, m0 = w * 16;

  // per-lane invariants: feature f0+n; D rows m0+q*4+r
  const float gmv = gam[f0 + n], btv = bet[f0 + n];
  float bias_g[4], mk[4];
#pragma unroll
  for (int g = 0; g < 4; ++g) bias_g[g] = bias_l[g * NH + f0 + n];
#pragma unroll
  for (int r = 0; r < 4; ++r) mk[r] = msk[(m0 + q * 4 + r) * NH + f0 + n];

  float cst[4] = {0.f, 0.f, 0.f, 0.f};  // cell state for (row m0+q*4+r, feature f0+n)

  for (int p = 0; p <= NSTEP; ++p) {
    const bool act = (layer == 0) ? (p < NSTEP) : (p >= 1);
    if (act) {
      const int t = (layer == 0) ? p : p - 1;
      // A operand: K 0..511 from (xs[t] | a[t]), K 512..1023 from h-slot t (state before step t)
      const unsigned short* A0 = (layer == 0) ? (xs + (size_t)t * SLAB) : (abq + (size_t)t * SLAB);
      const unsigned short* A1 = ((layer == 0) ? h1q : h2q) + (size_t)t * SLAB;
      const unsigned short* rowA0 = A0 + (m0 + n) * NH;   // A-frag row = lane&15
      const unsigned short* rowA1 = A1 + (m0 + n) * NH;

      f32x4 acc[4];
#pragma unroll
      for (int g = 0; g < 4; ++g) acc[g] = (f32x4){bias_g[g], bias_g[g], bias_g[g], bias_g[g]};

#pragma unroll
      for (int s = 0; s < 32; ++s) {
        const unsigned short* ap = (s < 16) ? (rowA0 + s * 32 + q * 8)
                                            : (rowA1 + (s - 16) * 32 + q * 8);
        bf16x8 af = *(const bf16x8*)ap;
#pragma unroll
        for (int g = 0; g < 4; ++g) {
          bf16x8 bf = *(const bf16x8*)&wlds[((s * 4 + g) * 64 + lane) * 8];
          acc[g] = __builtin_amdgcn_mfma_f32_16x16x32_bf16(af, bf, acc[g], 0, 0, 0);
        }
      }

      // LSTM cell (gate order i,f,g,o), all lane-local
      float hv[4], sum = 0.f, ssq = 0.f;
#pragma unroll
      for (int r = 0; r < 4; ++r) {
        float ig = sigm(acc[0][r]), fg = sigm(acc[1][r]);
        float gg = tanhf(acc[2][r]), og = sigm(acc[3][r]);
        cst[r] = fg * cst[r] + ig * gg;
        hv[r] = og * tanhf(cst[r]);
        sum += hv[r]; ssq += hv[r] * hv[r];
      }
      // batch stats for feature f0+n: reduce over q (shfl) then waves (LDS)
      sum += __shfl_xor(sum, 16); ssq += __shfl_xor(ssq, 16);
      sum += __shfl_xor(sum, 32); ssq += __shfl_xor(ssq, 32);
      if (q == 0) { red[w][0][n] = sum; red[w][1][n] = ssq; }
      __syncthreads();
      float s1 = red[0][0][n] + red[1][0][n] + red[2][0][n] + red[3][0][n];
      float s2 = red[0][1][n] + red[1][1][n] + red[2][1][n] + red[3][1][n];
      float mu = s1 * (1.f / 64.f);
      float var = s2 * (1.f / 64.f) - mu * mu;
      float rs = rsqrtf(var + 1e-5f);

      // h -> slot t+1 (write-once); a -> slot t. Cross-block state uses sc1 stores.
      unsigned short* hout = ((layer == 0) ? h1q : h2q) + (size_t)(t + 1) * SLAB;
      unsigned short* aout = (layer == 0) ? (abq + (size_t)t * SLAB) : (bseq + (size_t)t * SLAB);
#pragma unroll
      for (int r = 0; r < 4; ++r) {
        int row = m0 + q * 4 + r;
        float bn = (hv[r] - mu) * rs * gmv + btv;
        unsigned short hb = f2bf(hv[r]);
        unsigned short av = f2bf(bn * mk[r]);
        __hip_atomic_store(&hout[row * NH + f0 + n], hb, __ATOMIC_RELAXED, __HIP_MEMORY_SCOPE_AGENT);
        if (layer == 0) {
          __hip_atomic_store(&aout[row * NH + f0 + n], av, __ATOMIC_RELAXED, __HIP_MEMORY_SCOPE_AGENT);
        } else {
          aout[row * NH + f0 + n] = av;   // bseq: only read by k_dec (kernel-end flush covers it)
        }
      }
    }

    if (p < NSTEP) {   // no barrier needed after the final phase
      __syncthreads();                 // drains every wave's vmcnt -> sc1 stores are at L3
      if (threadIdx.x == 0) {
        __builtin_amdgcn_fence(__ATOMIC_RELEASE, "agent");   // leader-only; dirty set is tiny
        __hip_atomic_fetch_add(&bar[p], 1u, __ATOMIC_RELAXED, __HIP_MEMORY_SCOPE_AGENT);
        while (__hip_atomic_load(&bar[p], __ATOMIC_RELAXED, __HIP_MEMORY_SCOPE_AGENT) < 64u)
          __builtin_amdgcn_s_sleep(2);
      }
      __syncthreads();                 // release the other waves; consumers use plain loads
    }                                  // (write-once addresses cannot be stale in any cache)
  }
}

// ---------------- decoder GEMM ----------------
// out[b][v][t] = sum_h bseq[t][b][h]*wdec[v][h] + b_dec[v]
// block (nb, b): v-tile nb*128, batch b, all 128 t. Wave w: t rows [w*32, w*32+32).
__global__ void __launch_bounds__(256)
k_dec(const unsigned short* __restrict__ bseq, const unsigned short* __restrict__ wdec,
      const float* __restrict__ bdec, float* __restrict__ out) {
  const int nb = blockIdx.x, b = blockIdx.y;
  const int n0 = nb * 128;
  const int lane = threadIdx.x & 63, w = threadIdx.x >> 6;
  const int q = lane >> 4, n = lane & 15;

  f32x4 acc[2][8];
#pragma unroll
  for (int nt = 0; nt < 8; ++nt) {
    int v = n0 + nt * 16 + n;
    float bd = (v < NV) ? bdec[v] : 0.f;
#pragma unroll
    for (int mt = 0; mt < 2; ++mt) acc[mt][nt] = (f32x4){bd, bd, bd, bd};
  }
  const unsigned short* arow[2];
#pragma unroll
  for (int mt = 0; mt < 2; ++mt) {
    int t = w * 32 + mt * 16 + n;                       // A-frag row
    arow[mt] = bseq + ((size_t)t * NBATCH + b) * NH;
  }
  const unsigned short* brow[8];
#pragma unroll
  for (int nt = 0; nt < 8; ++nt) brow[nt] = wdec + (size_t)(n0 + nt * 16 + n) * NH;

#pragma unroll 4
  for (int s = 0; s < 16; ++s) {
    bf16x8 af[2];
#pragma unroll
    for (int mt = 0; mt < 2; ++mt) af[mt] = *(const bf16x8*)(arow[mt] + s * 32 + q * 8);
#pragma unroll
    for (int nt = 0; nt < 8; ++nt) {
      bf16x8 bf = *(const bf16x8*)(brow[nt] + s * 32 + q * 8);
#pragma unroll
      for (int mt = 0; mt < 2; ++mt)
        acc[mt][nt] = __builtin_amdgcn_mfma_f32_16x16x32_bf16(af[mt], bf, acc[mt][nt], 0, 0, 0);
    }
  }
  // store: lane's 4 acc regs = 4 consecutive t -> float4 (coalesced along t)
#pragma unroll
  for (int mt = 0; mt < 2; ++mt)
#pragma unroll
    for (int nt = 0; nt < 8; ++nt) {
      int v = n0 + nt * 16 + n;
      if (v < NV) {
        int t0 = w * 32 + mt * 16 + q * 4;
        *(f32x4*)(out + ((size_t)b * NV + v) * NSTEP + t0) = acc[mt][nt];
      }
    }
}

// ---------------- launch ----------------
extern "C" void kernel_launch(void* const* d_in, const int* in_sizes, int n_in,
                              void* d_out, int out_size, void* d_ws, size_t ws_size,
                              hipStream_t stream) {
  const int*   x     = (const int*)d_in[0];
  const float* emb   = (const float*)d_in[1];
  const float* Wih1  = (const float*)d_in[2];
  const float* Whh1  = (const float*)d_in[3];
  const float* bi1   = (const float*)d_in[4];
  const float* bh1   = (const float*)d_in[5];
  const float* g1    = (const float*)d_in[6];
  const float* be1   = (const float*)d_in[7];
  const float* m1    = (const float*)d_in[8];
  const float* Wih2  = (const float*)d_in[9];
  const float* Whh2  = (const float*)d_in[10];
  const float* bi2   = (const float*)d_in[11];
  const float* bh2   = (const float*)d_in[12];
  const float* g2    = (const float*)d_in[13];
  const float* be2   = (const float*)d_in[14];
  const float* m2    = (const float*)d_in[15];
  const float* Wdec  = (const float*)d_in[16];
  const float* bdec  = (const float*)d_in[17];
  float* out = (float*)d_out;
  char* ws = (char*)d_ws;

  unsigned short* xs    = (unsigned short*)(ws + OFF_XS);
  unsigned short* wp    = (unsigned short*)(ws + OFF_WP);
  unsigned short* wdec  = (unsigned short*)(ws + OFF_WDEC);
  float*          bias  = (float*)(ws + OFF_BIAS);
  unsigned short* h1q   = (unsigned short*)(ws + OFF_H1);
  unsigned short* abq   = (unsigned short*)(ws + OFF_AB);
  unsigned short* h2q   = (unsigned short*)(ws + OFF_H2);
  unsigned short* bseq  = (unsigned short*)(ws + OFF_BSEQ);
  unsigned*       bar   = (unsigned*)(ws + OFF_BAR);

  // zero initial-state slots + barrier counters (ws is poisoned 0xAA before every call)
  hipMemsetAsync(h1q, 0, SLAB * 2, stream);   // h1 slot 0
  hipMemsetAsync(h2q, 0, SLAB * 2, stream);   // h2 slot 0
  hipMemsetAsync(bar, 0, SZ_BAR, stream);

  k_xs   <<<dim3(16384), dim3(256), 0, stream>>>(x, emb, xs);
  k_wdec <<<dim3(16128), dim3(256), 0, stream>>>(Wdec, wdec);
  k_bias <<<dim3(16),    dim3(256), 0, stream>>>(bi1, bh1, bi2, bh2, bias);
  k_wpack<<<dim3(2048),  dim3(256), 0, stream>>>(Wih1, Whh1, Wih2, Whh2, wp);

  void* kargs[] = {(void*)&xs, (void*)&wp, (void*)&bias,
                   (void*)&g1, (void*)&be1, (void*)&m1,
                   (void*)&g2, (void*)&be2, (void*)&m2,
                   (void*)&h1q, (void*)&abq, (void*)&h2q, (void*)&bseq, (void*)&bar};
  hipLaunchCooperativeKernel((void*)k_recur, dim3(64), dim3(256), kargs, 0, stream);

  k_dec<<<dim3(63, 64), dim3(256), 0, stream>>>(bseq, wdec, bdec, out);
}

// Round 3
// 1683.992 us; speedup vs baseline: 1.8229x; 1.2788x over previous
//
#include <hip/hip_runtime.h>

typedef __attribute__((ext_vector_type(8))) short bf16x8;   // 8 bf16 (4 VGPRs)
typedef __attribute__((ext_vector_type(4))) float f32x4;    // MFMA acc

#define NBATCH 64
#define NH     512
#define NV     8001
#define NVP    8064      // padded V (63 tiles of 128)
#define NSTEP  128       // T-1
#define NG     2048      // 4*NH gate columns
#define SLAB   32768     // NBATCH*NH ushorts = one 64KB step-slab

// ---- workspace layout (bytes) ----
// State uses WRITE-ONCE sequence slabs: no address is ever rewritten, so
// consumer L1/L2 can never hold a stale copy -> plain cached loads are safe
// with NO acquire fence. Producers publish via sc1 (agent-scope) stores.
#define OFF_XS    ((size_t)0)
#define SZ_XS     ((size_t)NSTEP*SLAB*2)                 // 8 MB  bf16 [t][b][h]
#define OFF_WP    (OFF_XS + SZ_XS)
#define SZ_WP     ((size_t)2*2048*1024*2)                // 8 MB  frag-packed weights
#define OFF_WDEC  (OFF_WP + SZ_WP)
#define SZ_WDEC   ((size_t)NVP*NH*2)                     // 8.26 MB bf16, zero-padded rows
#define OFF_BIAS  (OFF_WDEC + SZ_WDEC)
#define SZ_BIAS   ((size_t)2*NG*4)                       // combined b_ih+b_hh per layer, fp32
#define OFF_H1    (OFF_BIAS + SZ_BIAS)
#define SZ_H1     ((size_t)(NSTEP+1)*SLAB*2)             // h1 after step t -> slot t+1 (slot 0 = zeros)
#define OFF_AB    (OFF_H1 + SZ_H1)
#define SZ_AB     ((size_t)NSTEP*SLAB*2)                 // a (post-BN1*mask1) at step t -> slot t
#define OFF_H2    (OFF_AB + SZ_AB)
#define SZ_H2     ((size_t)(NSTEP+1)*SLAB*2)             // h2 slots (slot 0 = zeros)
#define OFF_BSEQ  (OFF_H2 + SZ_H2)
#define SZ_BSEQ   ((size_t)NSTEP*SLAB*2)                 // 8 MB bf16 [t][b][h] (decoder input)
#define OFF_BAR   (OFF_BSEQ + SZ_BSEQ)
#define SZ_BAR    ((size_t)32768)                        // done1[128], done2[128] (64B stride), qcnt

__device__ __forceinline__ unsigned short f2bf(float x) {  // RNE float->bf16
  union { float f; unsigned u; } v; v.f = x;
  unsigned r = v.u + 0x7FFFu + ((v.u >> 16) & 1u);
  return (unsigned short)(r >> 16);
}
__device__ __forceinline__ float sigm(float x) { return 1.f / (1.f + __expf(-x)); }

// Spin until *f >= 32. Relaxed agent load (bypasses L1/L2); the asm memory
// clobber stops the compiler hoisting subsequent data loads above the wait.
// SLP is a template param because __builtin_amdgcn_s_sleep needs an immediate.
template <int SLP>
__device__ __forceinline__ void waitflag(unsigned* f) {
  while (__hip_atomic_load(f, __ATOMIC_RELAXED, __HIP_MEMORY_SCOPE_AGENT) < 32u)
    __builtin_amdgcn_s_sleep(SLP);
  asm volatile("" ::: "memory");
}

// ---------------- prep kernels ----------------

// xs[t][b][h] = bf16(emb[x[b][t]][h]), vectorized x8
__global__ void k_xs(const int* __restrict__ x, const float* __restrict__ emb,
                     unsigned short* __restrict__ xs) {
  int idx = blockIdx.x * 256 + threadIdx.x;          // 524288 threads, 8 bf16 each
  int t = idx >> 12, b = (idx >> 6) & 63, h8 = idx & 63;
  const float* src = emb + (size_t)x[b * 129 + t] * NH + h8 * 8;
  float4 a = *(const float4*)src, c = *(const float4*)(src + 4);
  unsigned short tmp[8] = {f2bf(a.x), f2bf(a.y), f2bf(a.z), f2bf(a.w),
                           f2bf(c.x), f2bf(c.y), f2bf(c.z), f2bf(c.w)};
  *(uint4*)(xs + (size_t)idx * 8) = *(const uint4*)tmp;
}

// wdec[v][h] bf16, zero pad rows v>=8001, vectorized x8
__global__ void k_wdec(const float* __restrict__ W, unsigned short* __restrict__ wdec) {
  int idx = blockIdx.x * 256 + threadIdx.x;          // 516096 threads
  int v = idx >> 6, h8 = idx & 63;
  unsigned short tmp[8] = {0, 0, 0, 0, 0, 0, 0, 0};
  if (v < NV) {
    const float* src = W + (size_t)v * NH + h8 * 8;
    float4 a = *(const float4*)src, c = *(const float4*)(src + 4);
    tmp[0] = f2bf(a.x); tmp[1] = f2bf(a.y); tmp[2] = f2bf(a.z); tmp[3] = f2bf(a.w);
    tmp[4] = f2bf(c.x); tmp[5] = f2bf(c.y); tmp[6] = f2bf(c.z); tmp[7] = f2bf(c.w);
  }
  *(uint4*)(wdec + (size_t)idx * 8) = *(const uint4*)tmp;
}

__global__ void k_bias(const float* __restrict__ bi1, const float* __restrict__ bh1,
                       const float* __restrict__ bi2, const float* __restrict__ bh2,
                       float* __restrict__ bias) {
  int i = blockIdx.x * 256 + threadIdx.x;            // 4096 threads
  bias[i] = (i < NG) ? (bi1[i] + bh1[i]) : (bi2[i - NG] + bh2[i - NG]);
}

// Pack recurrence weights into MFMA B-fragment order.
// Layout: [layer][lb(32)][s(32)][g(4)][lane(64)][8 bf16]; r = g*512+lb*16+(lane&15), k = s*32+(lane>>4)*8
__global__ void k_wpack(const float* __restrict__ Wih1, const float* __restrict__ Whh1,
                        const float* __restrict__ Wih2, const float* __restrict__ Whh2,
                        unsigned short* __restrict__ wp) {
  int tid = blockIdx.x * 256 + threadIdx.x;          // 524288 threads
  int l = tid & 63, g = (tid >> 6) & 3, s = (tid >> 8) & 31, lb = (tid >> 13) & 31, layer = tid >> 18;
  int n = l & 15, q = l >> 4;
  int r = g * NH + lb * 16 + n;
  int k0 = s * 32 + q * 8;
  const float* Wih = layer ? Wih2 : Wih1;
  const float* Whh = layer ? Whh2 : Whh1;
  const float* src = (k0 < NH) ? (Wih + (size_t)r * NH + k0) : (Whh + (size_t)r * NH + (k0 - NH));
  unsigned short tmp[8];
#pragma unroll
  for (int j = 0; j < 8; ++j) tmp[j] = f2bf(src[j]);
  *(uint4*)(wp + (size_t)tid * 8) = *(const uint4*)tmp;
}

// ---------------- fused cooperative kernel ----------------
// 256 blocks x 256 (1 block/CU, LDS-bound).
// Blocks 0..63: recurrence. Block = (layer = bid>>5, lb = bid&31) owns 16 features.
// Sync: per-step done counters (write-once, 64B-strided) instead of a global barrier.
//   producer: sc1 stores -> __syncthreads (drains all waves' vmcnt) -> atomicAdd done[t]
//   consumer: relaxed-agent poll on done[t] -> plain cached loads (write-once slabs)
// Layer-0 overlaps its xs-half MFMAs with the wait; layer-0 runs ahead of layer-1 freely.
// All 256 blocks then drain a dynamic queue of decoder chunks (nb, b, tc), each gated
// on done2[tc*32+31]; ~3/4 of the decode overlaps the recurrence on the idle 192 CUs.
__global__ void __launch_bounds__(256, 1)
k_main(const unsigned short* __restrict__ xs, const unsigned short* __restrict__ wpack,
       const float* __restrict__ bias,
       const float* __restrict__ gamma1, const float* __restrict__ beta1, const float* __restrict__ mask1,
       const float* __restrict__ gamma2, const float* __restrict__ beta2, const float* __restrict__ mask2,
       unsigned short* __restrict__ h1q, unsigned short* __restrict__ abq,
       unsigned short* __restrict__ h2q, unsigned short* __restrict__ bseq,
       unsigned* __restrict__ bar,
       const unsigned short* __restrict__ wdec, const float* __restrict__ bdec,
       float* __restrict__ out) {
  __shared__ unsigned short wlds[32 * 4 * 64 * 8];   // 128 KB: block's weight strip, frag order
  __shared__ float red[4][2][16];                    // BN cross-wave partials

  unsigned* done1 = bar;              // done1[t] at bar[t*16]   : layer-0 step t complete
  unsigned* done2 = bar + 2048;       // done2[t] at bar[2048+t*16]
  unsigned* qcnt  = bar + 4096;       // decoder work-queue counter

  const int bid = blockIdx.x;
  const int lane = threadIdx.x & 63, w = threadIdx.x >> 6;
  const int q = lane >> 4, n = lane & 15;

  if (bid < 64) {
    const int layer = bid >> 5, lb = bid & 31, f0 = lb * 16;
    const float* gam = layer ? gamma2 : gamma1;
    const float* bet = layer ? beta2 : beta1;
    const float* msk = layer ? mask2 : mask1;
    const float* bias_l = bias + layer * NG;

    { // stage weights -> LDS (contiguous, coalesced)
      const uint4* src = (const uint4*)(wpack + (size_t)bid * (32 * 4 * 64 * 8));
      uint4* dst = (uint4*)wlds;
      for (int i = threadIdx.x; i < 32 * 4 * 64; i += 256) dst[i] = src[i];
    }
    __syncthreads();

    const int m0 = w * 16;
    const float gmv = gam[f0 + n], btv = bet[f0 + n];
    float bias_g[4], mk[4];
#pragma unroll
    for (int g = 0; g < 4; ++g) bias_g[g] = bias_l[g * NH + f0 + n];
#pragma unroll
    for (int r = 0; r < 4; ++r) mk[r] = msk[(m0 + q * 4 + r) * NH + f0 + n];

    float cst[4] = {0.f, 0.f, 0.f, 0.f};

    for (int t = 0; t < NSTEP; ++t) {
      f32x4 acc[4];
#pragma unroll
      for (int g = 0; g < 4; ++g) acc[g] = (f32x4){bias_g[g], bias_g[g], bias_g[g], bias_g[g]};

      if (layer == 0) {
        // xs-half first: no dependency -> overlaps the wait for peers' h1
        const unsigned short* rowA0 = xs + (size_t)t * SLAB + (m0 + n) * NH;
#pragma unroll
        for (int s = 0; s < 16; ++s) {
          bf16x8 af = *(const bf16x8*)(rowA0 + s * 32 + q * 8);
#pragma unroll
          for (int g = 0; g < 4; ++g)
            acc[g] = __builtin_amdgcn_mfma_f32_16x16x32_bf16(
                af, *(const bf16x8*)&wlds[((s * 4 + g) * 64 + lane) * 8], acc[g], 0, 0, 0);
        }
        if (t > 0) waitflag<1>(done1 + (t - 1) * 16);   // h1 slot t ready
        const unsigned short* rowA1 = h1q + (size_t)t * SLAB + (m0 + n) * NH;
#pragma unroll
        for (int s = 0; s < 16; ++s) {
          bf16x8 af = *(const bf16x8*)(rowA1 + s * 32 + q * 8);
#pragma unroll
          for (int g = 0; g < 4; ++g)
            acc[g] = __builtin_amdgcn_mfma_f32_16x16x32_bf16(
                af, *(const bf16x8*)&wlds[(((s + 16) * 4 + g) * 64 + lane) * 8], acc[g], 0, 0, 0);
        }
      } else {
        if (t > 0) waitflag<1>(done2 + (t - 1) * 16);   // h2 slot t ready
        const unsigned short* rowA1 = h2q + (size_t)t * SLAB + (m0 + n) * NH;
#pragma unroll
        for (int s = 0; s < 16; ++s) {
          bf16x8 af = *(const bf16x8*)(rowA1 + s * 32 + q * 8);
#pragma unroll
          for (int g = 0; g < 4; ++g)
            acc[g] = __builtin_amdgcn_mfma_f32_16x16x32_bf16(
                af, *(const bf16x8*)&wlds[(((s + 16) * 4 + g) * 64 + lane) * 8], acc[g], 0, 0, 0);
        }
        waitflag<1>(done1 + t * 16);                    // ab[t] ready (layer-0 step t)
        const unsigned short* rowA0 = abq + (size_t)t * SLAB + (m0 + n) * NH;
#pragma unroll
        for (int s = 0; s < 16; ++s) {
          bf16x8 af = *(const bf16x8*)(rowA0 + s * 32 + q * 8);
#pragma unroll
          for (int g = 0; g < 4; ++g)
            acc[g] = __builtin_amdgcn_mfma_f32_16x16x32_bf16(
                af, *(const bf16x8*)&wlds[((s * 4 + g) * 64 + lane) * 8], acc[g], 0, 0, 0);
        }
      }

      // LSTM cell (gate order i,f,g,o), all lane-local
      float hv[4], sum = 0.f, ssq = 0.f;
#pragma unroll
      for (int r = 0; r < 4; ++r) {
        float ig = sigm(acc[0][r]), fg = sigm(acc[1][r]);
        float gg = tanhf(acc[2][r]), og = sigm(acc[3][r]);
        cst[r] = fg * cst[r] + ig * gg;
        hv[r] = og * tanhf(cst[r]);
        sum += hv[r]; ssq += hv[r] * hv[r];
      }
      // batch stats for feature f0+n: reduce over q (shfl) then waves (LDS)
      sum += __shfl_xor(sum, 16); ssq += __shfl_xor(ssq, 16);
      sum += __shfl_xor(sum, 32); ssq += __shfl_xor(ssq, 32);
      if (q == 0) { red[w][0][n] = sum; red[w][1][n] = ssq; }
      __syncthreads();
      float s1 = red[0][0][n] + red[1][0][n] + red[2][0][n] + red[3][0][n];
      float s2 = red[0][1][n] + red[1][1][n] + red[2][1][n] + red[3][1][n];
      float mu = s1 * (1.f / 64.f);
      float var = s2 * (1.f / 64.f) - mu * mu;
      float rs = rsqrtf(var + 1e-5f);

      // h -> slot t+1 (write-once); a -> slot t. All cross-block state: sc1 stores.
      unsigned short* hout = ((layer == 0) ? h1q : h2q) + (size_t)(t + 1) * SLAB;
      unsigned short* aout = ((layer == 0) ? abq : bseq) + (size_t)t * SLAB;
#pragma unroll
      for (int r = 0; r < 4; ++r) {
        int row = m0 + q * 4 + r;
        float bn = (hv[r] - mu) * rs * gmv + btv;
        unsigned short hb = f2bf(hv[r]);
        unsigned short av = f2bf(bn * mk[r]);
        __hip_atomic_store(&hout[row * NH + f0 + n], hb, __ATOMIC_RELAXED, __HIP_MEMORY_SCOPE_AGENT);
        __hip_atomic_store(&aout[row * NH + f0 + n], av, __ATOMIC_RELAXED, __HIP_MEMORY_SCOPE_AGENT);
      }

      __syncthreads();   // drains every wave's vmcnt -> all sc1 stores at coherence point
      if (threadIdx.x == 0)
        atomicAdd((layer ? done2 : done1) + t * 16, 1u);   // fire-and-forget signal
      // also protects red[] reuse next step (barrier between read and rewrite)
    }
  }

  // ---------------- decoder (all blocks; waves independent, NO __syncthreads here) ----
  // chunk c: tc = c>>12 (t-range [tc*32, tc*32+32)), r = c&4095 (skip r>=4032),
  //          nb = r>>6 (v-tile nb*128), b = r&63. Queue is tc-ordered so waves
  //          naturally consume chunks as done2 advances; after the recurrence ends,
  //          all 1024 waves share the remaining tc=3 chunks.
  while (true) {
    unsigned c = 0;
    if (lane == 0) c = atomicAdd(qcnt, 1u);
    c = __shfl(c, 0);
    if (c >= 16384u) break;
    unsigned tc = c >> 12, r = c & 4095u;
    if (r >= 4032u) continue;
    int nb = (int)(r >> 6), b = (int)(r & 63u);
    waitflag<8>(done2 + (tc * 32 + 31) * 16);   // bseq[tc*32 .. tc*32+31] final

    const int n0 = nb * 128;
    f32x4 acc[2][8];
#pragma unroll
    for (int nt = 0; nt < 8; ++nt) {
      int v = n0 + nt * 16 + n;
      float bd = (v < NV) ? bdec[v] : 0.f;
      acc[0][nt] = (f32x4){bd, bd, bd, bd};
      acc[1][nt] = acc[0][nt];
    }
    const unsigned short* arow[2];
#pragma unroll
    for (int mt = 0; mt < 2; ++mt)
      arow[mt] = bseq + ((size_t)(tc * 32 + mt * 16 + n) * NBATCH + b) * NH;
    const unsigned short* brow[8];
#pragma unroll
    for (int nt = 0; nt < 8; ++nt) brow[nt] = wdec + (size_t)(n0 + nt * 16 + n) * NH;

#pragma unroll 4
    for (int s = 0; s < 16; ++s) {
      bf16x8 af[2];
#pragma unroll
      for (int mt = 0; mt < 2; ++mt) af[mt] = *(const bf16x8*)(arow[mt] + s * 32 + q * 8);
#pragma unroll
      for (int nt = 0; nt < 8; ++nt) {
        bf16x8 bf = *(const bf16x8*)(brow[nt] + s * 32 + q * 8);
#pragma unroll
        for (int mt = 0; mt < 2; ++mt)
          acc[mt][nt] = __builtin_amdgcn_mfma_f32_16x16x32_bf16(af[mt], bf, acc[mt][nt], 0, 0, 0);
      }
    }
#pragma unroll
    for (int mt = 0; mt < 2; ++mt)
#pragma unroll
      for (int nt = 0; nt < 8; ++nt) {
        int v = n0 + nt * 16 + n;
        if (v < NV) {
          int t0 = (int)tc * 32 + mt * 16 + q * 4;
          *(f32x4*)(out + ((size_t)b * NV + v) * NSTEP + t0) = acc[mt][nt];
        }
      }
  }
}

// ---------------- launch ----------------
extern "C" void kernel_launch(void* const* d_in, const int* in_sizes, int n_in,
                              void* d_out, int out_size, void* d_ws, size_t ws_size,
                              hipStream_t stream) {
  const int*   x     = (const int*)d_in[0];
  const float* emb   = (const float*)d_in[1];
  const float* Wih1  = (const float*)d_in[2];
  const float* Whh1  = (const float*)d_in[3];
  const float* bi1   = (const float*)d_in[4];
  const float* bh1   = (const float*)d_in[5];
  const float* g1    = (const float*)d_in[6];
  const float* be1   = (const float*)d_in[7];
  const float* m1    = (const float*)d_in[8];
  const float* Wih2  = (const float*)d_in[9];
  const float* Whh2  = (const float*)d_in[10];
  const float* bi2   = (const float*)d_in[11];
  const float* bh2   = (const float*)d_in[12];
  const float* g2    = (const float*)d_in[13];
  const float* be2   = (const float*)d_in[14];
  const float* m2    = (const float*)d_in[15];
  const float* Wdec  = (const float*)d_in[16];
  const float* bdec  = (const float*)d_in[17];
  float* out = (float*)d_out;
  char* ws = (char*)d_ws;

  unsigned short* xs    = (unsigned short*)(ws + OFF_XS);
  unsigned short* wp    = (unsigned short*)(ws + OFF_WP);
  unsigned short* wdec  = (unsigned short*)(ws + OFF_WDEC);
  float*          bias  = (float*)(ws + OFF_BIAS);
  unsigned short* h1q   = (unsigned short*)(ws + OFF_H1);
  unsigned short* abq   = (unsigned short*)(ws + OFF_AB);
  unsigned short* h2q   = (unsigned short*)(ws + OFF_H2);
  unsigned short* bseq  = (unsigned short*)(ws + OFF_BSEQ);
  unsigned*       bar   = (unsigned*)(ws + OFF_BAR);

  // zero initial-state slots + flag/queue counters (ws is poisoned 0xAA before every call)
  (void)hipMemsetAsync(h1q, 0, SLAB * 2, stream);   // h1 slot 0
  (void)hipMemsetAsync(h2q, 0, SLAB * 2, stream);   // h2 slot 0
  (void)hipMemsetAsync(bar, 0, SZ_BAR, stream);

  k_xs   <<<dim3(2048), dim3(256), 0, stream>>>(x, emb, xs);
  k_wdec <<<dim3(2016), dim3(256), 0, stream>>>(Wdec, wdec);
  k_bias <<<dim3(16),   dim3(256), 0, stream>>>(bi1, bh1, bi2, bh2, bias);
  k_wpack<<<dim3(2048), dim3(256), 0, stream>>>(Wih1, Whh1, Wih2, Whh2, wp);

  void* kargs[] = {(void*)&xs, (void*)&wp, (void*)&bias,
                   (void*)&g1, (void*)&be1, (void*)&m1,
                   (void*)&g2, (void*)&be2, (void*)&m2,
                   (void*)&h1q, (void*)&abq, (void*)&h2q, (void*)&bseq, (void*)&bar,
                   (void*)&wdec, (void*)&bdec, (void*)&out};
  (void)hipLaunchCooperativeKernel((void*)k_main, dim3(256), dim3(256), kargs, 0, stream);
}

// Round 4
// 1640.814 us; speedup vs baseline: 1.8708x; 1.0263x over previous
//
#include <hip/hip_runtime.h>

typedef __attribute__((ext_vector_type(8))) short bf16x8;   // 8 bf16 (4 VGPRs)
typedef __attribute__((ext_vector_type(4))) float f32x4;    // MFMA acc

#define NBATCH 64
#define NH     512
#define NV     8001
#define NVP    8064      // padded V (63 tiles of 128)
#define NSTEP  128       // T-1
#define NG     2048      // 4*NH gate columns
#define SLAB   32768     // NBATCH*NH ushorts = one 64KB step-slab

// ---- workspace layout (bytes) ----
// State uses WRITE-ONCE sequence slabs: no address is ever rewritten, so
// consumer L1/L2 can never hold a stale copy -> plain cached loads are safe
// with NO acquire fence. Producers publish via sc1 (agent-scope) stores.
#define OFF_XS    ((size_t)0)
#define SZ_XS     ((size_t)NSTEP*SLAB*2)                 // 8 MB  bf16 [t][b][h]
#define OFF_WP    (OFF_XS + SZ_XS)
#define SZ_WP     ((size_t)2*2048*1024*2)                // 8 MB  frag-packed weights
#define OFF_WDEC  (OFF_WP + SZ_WP)
#define SZ_WDEC   ((size_t)NVP*NH*2)                     // 8.26 MB bf16, zero-padded rows
#define OFF_BIAS  (OFF_WDEC + SZ_WDEC)
#define SZ_BIAS   ((size_t)2*NG*4)                       // combined b_ih+b_hh per layer, fp32
#define OFF_H1    (OFF_BIAS + SZ_BIAS)
#define SZ_H1     ((size_t)(NSTEP+1)*SLAB*2)             // h1 after step t -> slot t+1 (slot 0 = zeros)
#define OFF_AB    (OFF_H1 + SZ_H1)
#define SZ_AB     ((size_t)NSTEP*SLAB*2)                 // a (post-BN1*mask1) at step t -> slot t
#define OFF_H2    (OFF_AB + SZ_AB)
#define SZ_H2     ((size_t)(NSTEP+1)*SLAB*2)             // h2 slots (slot 0 = zeros)
#define OFF_BSEQ  (OFF_H2 + SZ_H2)
#define SZ_BSEQ   ((size_t)NSTEP*SLAB*2)                 // 8 MB bf16 [t][b][h] (decoder input)
#define OFF_BAR   (OFF_BSEQ + SZ_BSEQ)
#define SZ_BAR    ((size_t)65536)                        // flags, 128B-strided

// flag indices (u32 units, 32 u32 = 128 B = one L3 line per flag)
#define F_D1(t)   ((t) * 32)            // done1[t]
#define F_D2(t)   (4096 + (t) * 32)     // done2[t]
#define F_QCNT    8192                  // decoder work-queue counter
#define F_GBAR    8224                  // prologue grid barrier
#define F_DRDY(c) (8320 + (c) * 32)     // decode-ready per tc (0..3)

__device__ __forceinline__ unsigned short f2bf(float x) {  // RNE float->bf16
  union { float f; unsigned u; } v; v.f = x;
  unsigned r = v.u + 0x7FFFu + ((v.u >> 16) & 1u);
  return (unsigned short)(r >> 16);
}
__device__ __forceinline__ float sigm(float x) { return 1.f / (1.f + __expf(-x)); }

// Spin until *f >= 32 (all 32 producer blocks arrived). Relaxed agent load;
// asm clobber stops hoisting of subsequent data loads above the wait.
template <int SLP>
__device__ __forceinline__ void waitflag(unsigned* f) {
  while (__hip_atomic_load(f, __ATOMIC_RELAXED, __HIP_MEMORY_SCOPE_AGENT) < 32u)
    __builtin_amdgcn_s_sleep(SLP);
  asm volatile("" ::: "memory");
}

// Spin until *f != 0. First-check fast path; long sleep in the loop (only the
// initial gated wait ever loops -> keeps idle-wave poll traffic off the L3).
template <int SLP>
__device__ __forceinline__ void waitone(unsigned* f) {
  if (!__hip_atomic_load(f, __ATOMIC_RELAXED, __HIP_MEMORY_SCOPE_AGENT)) {
    do { __builtin_amdgcn_s_sleep(SLP); }
    while (!__hip_atomic_load(f, __ATOMIC_RELAXED, __HIP_MEMORY_SCOPE_AGENT));
  }
  asm volatile("" ::: "memory");
}

struct KArgs {
  const int* x; const float* emb;
  const float* Wih1; const float* Whh1; const float* bi1; const float* bh1;
  const float* g1; const float* be1; const float* m1;
  const float* Wih2; const float* Whh2; const float* bi2; const float* bh2;
  const float* g2; const float* be2; const float* m2;
  const float* Wdec; const float* bdec;
  unsigned short* xs; unsigned short* wp; unsigned short* wdec; float* bias;
  unsigned short* h1q; unsigned short* abq; unsigned short* h2q; unsigned short* bseq;
  unsigned* bar; float* out;
};

// ---------------- single fused cooperative kernel ----------------
// 256 blocks x 256 (1 block/CU, LDS-bound).
// Phase A (all blocks): prep — bias, xs (emb gather->bf16), wdec, wpack, state
//   slot-0 zero; then hand-rolled grid barrier (leader release-fence publishes
//   the plain prep stores cross-XCD; consumers have no stale copies: write-once).
// Phase B (blocks 0..63): LSTM recurrence, per-step done-flag signaling.
// Phase C (all blocks): decoder GEMM work queue, gated per-32-step chunk on
//   dready[tc] (dedicated lines, long-sleep polling -> no L3 flag storm).
__global__ void __launch_bounds__(256, 1) k_main(KArgs a) {
  __shared__ unsigned short wlds[32 * 4 * 64 * 8];   // 128 KB: weight strip, frag order
  __shared__ float red[4][2][16];                    // BN cross-wave partials

  unsigned* bar = a.bar;
  const int bid = blockIdx.x;
  const int lane = threadIdx.x & 63, w = threadIdx.x >> 6;
  const int q = lane >> 4, n = lane & 15;

  // ---------------- Phase A: prep (grid-stride over 65536 threads) ----------
  {
    const int gtid = bid * 256 + threadIdx.x;
    // bias: combined b_ih + b_hh, both layers
    if (gtid < 4096)
      a.bias[gtid] = (gtid < NG) ? (a.bi1[gtid] + a.bh1[gtid])
                                 : (a.bi2[gtid - NG] + a.bh2[gtid - NG]);
    // zero h1/h2 slot 0 (4096 uint4 each)
    if (gtid < 4096) {
      ((uint4*)a.h1q)[gtid] = (uint4){0, 0, 0, 0};
      ((uint4*)a.h2q)[gtid] = (uint4){0, 0, 0, 0};
    }
    // xs[t][b][h] = bf16(emb[x[b][t]][h]), 8 bf16 per item
    for (int i = gtid; i < 524288; i += 65536) {
      int t = i >> 12, b = (i >> 6) & 63, h8 = i & 63;
      const float* src = a.emb + (size_t)a.x[b * 129 + t] * NH + h8 * 8;
      float4 u = *(const float4*)src, v = *(const float4*)(src + 4);
      unsigned short tmp[8] = {f2bf(u.x), f2bf(u.y), f2bf(u.z), f2bf(u.w),
                               f2bf(v.x), f2bf(v.y), f2bf(v.z), f2bf(v.w)};
      *(uint4*)(a.xs + (size_t)i * 8) = *(const uint4*)tmp;
    }
    // wdec[v][h] bf16, zero pad rows v>=NV
    for (int i = gtid; i < 516096; i += 65536) {
      int v = i >> 6, h8 = i & 63;
      unsigned short tmp[8] = {0, 0, 0, 0, 0, 0, 0, 0};
      if (v < NV) {
        const float* src = a.Wdec + (size_t)v * NH + h8 * 8;
        float4 u = *(const float4*)src, vv = *(const float4*)(src + 4);
        tmp[0] = f2bf(u.x); tmp[1] = f2bf(u.y); tmp[2] = f2bf(u.z); tmp[3] = f2bf(u.w);
        tmp[4] = f2bf(vv.x); tmp[5] = f2bf(vv.y); tmp[6] = f2bf(vv.z); tmp[7] = f2bf(vv.w);
      }
      *(uint4*)(a.wdec + (size_t)i * 8) = *(const uint4*)tmp;
    }
    // wpack: [layer][lb(32)][s(32)][g(4)][lane(64)][8]; r=g*512+lb*16+(l&15), k=s*32+(l>>4)*8
    for (int i = gtid; i < 524288; i += 65536) {
      int l = i & 63, g = (i >> 6) & 3, s = (i >> 8) & 31, lb = (i >> 13) & 31, layer = i >> 18;
      int nn = l & 15, qq = l >> 4;
      int r = g * NH + lb * 16 + nn;
      int k0 = s * 32 + qq * 8;
      const float* Wih = layer ? a.Wih2 : a.Wih1;
      const float* Whh = layer ? a.Whh2 : a.Whh1;
      const float* src = (k0 < NH) ? (Wih + (size_t)r * NH + k0) : (Whh + (size_t)r * NH + (k0 - NH));
      unsigned short tmp[8];
#pragma unroll
      for (int j = 0; j < 8; ++j) tmp[j] = f2bf(src[j]);
      *(uint4*)(a.wp + (size_t)i * 8) = *(const uint4*)tmp;
    }
  }
  // grid barrier: leader release-fences (wbl2 flushes this XCD's dirty prep
  // lines to L3) after the block's stores drained, then counts in.
  __syncthreads();
  if (threadIdx.x == 0) {
    __builtin_amdgcn_fence(__ATOMIC_RELEASE, "agent");
    __hip_atomic_fetch_add(bar + F_GBAR, 1u, __ATOMIC_RELAXED, __HIP_MEMORY_SCOPE_AGENT);
    while (__hip_atomic_load(bar + F_GBAR, __ATOMIC_RELAXED, __HIP_MEMORY_SCOPE_AGENT) < 256u)
      __builtin_amdgcn_s_sleep(8);
  }
  __syncthreads();
  asm volatile("" ::: "memory");

  // ---------------- Phase B: recurrence (blocks 0..63) ----------------------
  if (bid < 64) {
    const int layer = bid >> 5, lb = bid & 31, f0 = lb * 16;
    const float* gam = layer ? a.g2 : a.g1;
    const float* bet = layer ? a.be2 : a.be1;
    const float* msk = layer ? a.m2 : a.m1;
    const float* bias_l = a.bias + layer * NG;
    unsigned* myflag = bar + (layer ? F_D2(0) : F_D1(0));

    { // stage weights -> LDS (contiguous, coalesced)
      const uint4* src = (const uint4*)(a.wp + (size_t)bid * (32 * 4 * 64 * 8));
      uint4* dst = (uint4*)wlds;
      for (int i = threadIdx.x; i < 32 * 4 * 64; i += 256) dst[i] = src[i];
    }
    __syncthreads();

    const int m0 = w * 16;
    const float gmv = gam[f0 + n], btv = bet[f0 + n];
    float bias_g[4], mk[4];
#pragma unroll
    for (int g = 0; g < 4; ++g) bias_g[g] = bias_l[g * NH + f0 + n];
#pragma unroll
    for (int r = 0; r < 4; ++r) mk[r] = msk[(m0 + q * 4 + r) * NH + f0 + n];

    float cst[4] = {0.f, 0.f, 0.f, 0.f};

    for (int t = 0; t < NSTEP; ++t) {
      f32x4 acc[4];
#pragma unroll
      for (int g = 0; g < 4; ++g) acc[g] = (f32x4){bias_g[g], bias_g[g], bias_g[g], bias_g[g]};

      if (layer == 0) {
        // xs-half first: no dependency -> overlaps the wait for peers' h1
        const unsigned short* rowA0 = a.xs + (size_t)t * SLAB + (m0 + n) * NH;
#pragma unroll
        for (int s = 0; s < 16; ++s) {
          bf16x8 af = *(const bf16x8*)(rowA0 + s * 32 + q * 8);
#pragma unroll
          for (int g = 0; g < 4; ++g)
            acc[g] = __builtin_amdgcn_mfma_f32_16x16x32_bf16(
                af, *(const bf16x8*)&wlds[((s * 4 + g) * 64 + lane) * 8], acc[g], 0, 0, 0);
        }
        if (t > 0) waitflag<1>(bar + F_D1(t - 1));      // h1 slot t ready
        const unsigned short* rowA1 = a.h1q + (size_t)t * SLAB + (m0 + n) * NH;
#pragma unroll
        for (int s = 0; s < 16; ++s) {
          bf16x8 af = *(const bf16x8*)(rowA1 + s * 32 + q * 8);
#pragma unroll
          for (int g = 0; g < 4; ++g)
            acc[g] = __builtin_amdgcn_mfma_f32_16x16x32_bf16(
                af, *(const bf16x8*)&wlds[(((s + 16) * 4 + g) * 64 + lane) * 8], acc[g], 0, 0, 0);
        }
      } else {
        if (t > 0) waitflag<1>(bar + F_D2(t - 1));      // h2 slot t ready
        const unsigned short* rowA1 = a.h2q + (size_t)t * SLAB + (m0 + n) * NH;
#pragma unroll
        for (int s = 0; s < 16; ++s) {
          bf16x8 af = *(const bf16x8*)(rowA1 + s * 32 + q * 8);
#pragma unroll
          for (int g = 0; g < 4; ++g)
            acc[g] = __builtin_amdgcn_mfma_f32_16x16x32_bf16(
                af, *(const bf16x8*)&wlds[(((s + 16) * 4 + g) * 64 + lane) * 8], acc[g], 0, 0, 0);
        }
        waitflag<1>(bar + F_D1(t));                     // ab[t] ready (layer-0 step t)
        const unsigned short* rowA0 = a.abq + (size_t)t * SLAB + (m0 + n) * NH;
#pragma unroll
        for (int s = 0; s < 16; ++s) {
          bf16x8 af = *(const bf16x8*)(rowA0 + s * 32 + q * 8);
#pragma unroll
          for (int g = 0; g < 4; ++g)
            acc[g] = __builtin_amdgcn_mfma_f32_16x16x32_bf16(
                af, *(const bf16x8*)&wlds[((s * 4 + g) * 64 + lane) * 8], acc[g], 0, 0, 0);
        }
      }

      // LSTM cell (gate order i,f,g,o), all lane-local
      float hv[4], sum = 0.f, ssq = 0.f;
#pragma unroll
      for (int r = 0; r < 4; ++r) {
        float ig = sigm(acc[0][r]), fg = sigm(acc[1][r]);
        float gg = tanhf(acc[2][r]), og = sigm(acc[3][r]);
        cst[r] = fg * cst[r] + ig * gg;
        hv[r] = og * tanhf(cst[r]);
        sum += hv[r]; ssq += hv[r] * hv[r];
      }
      // batch stats for feature f0+n: reduce over q (shfl) then waves (LDS)
      sum += __shfl_xor(sum, 16); ssq += __shfl_xor(ssq, 16);
      sum += __shfl_xor(sum, 32); ssq += __shfl_xor(ssq, 32);
      if (q == 0) { red[w][0][n] = sum; red[w][1][n] = ssq; }
      __syncthreads();
      float s1 = red[0][0][n] + red[1][0][n] + red[2][0][n] + red[3][0][n];
      float s2 = red[0][1][n] + red[1][1][n] + red[2][1][n] + red[3][1][n];
      float mu = s1 * (1.f / 64.f);
      float var = s2 * (1.f / 64.f) - mu * mu;
      float rs = rsqrtf(var + 1e-5f);

      // h -> slot t+1 (write-once); a -> slot t. All cross-block state: sc1 stores.
      unsigned short* hout = ((layer == 0) ? a.h1q : a.h2q) + (size_t)(t + 1) * SLAB;
      unsigned short* aout = ((layer == 0) ? a.abq : a.bseq) + (size_t)t * SLAB;
#pragma unroll
      for (int r = 0; r < 4; ++r) {
        int row = m0 + q * 4 + r;
        float bn = (hv[r] - mu) * rs * gmv + btv;
        unsigned short hb = f2bf(hv[r]);
        unsigned short av = f2bf(bn * mk[r]);
        __hip_atomic_store(&hout[row * NH + f0 + n], hb, __ATOMIC_RELAXED, __HIP_MEMORY_SCOPE_AGENT);
        __hip_atomic_store(&aout[row * NH + f0 + n], av, __ATOMIC_RELAXED, __HIP_MEMORY_SCOPE_AGENT);
      }

      __syncthreads();   // drains every wave's vmcnt -> all sc1 stores at coherence point
      if (threadIdx.x == 0) {
        unsigned old = __hip_atomic_fetch_add(myflag + t * 32, 1u,
                                              __ATOMIC_RELAXED, __HIP_MEMORY_SCOPE_AGENT);
        // 32nd layer-1 arriver of a chunk-boundary step releases the decoder chunk
        if (layer == 1 && old == 31u && (t & 31) == 31)
          __hip_atomic_store(bar + F_DRDY(t >> 5), 1u,
                             __ATOMIC_RELAXED, __HIP_MEMORY_SCOPE_AGENT);
      }
      // (the syncthreads also protects red[] reuse next step)
    }
  }

  // ---------------- Phase C: decoder work queue (all blocks) -----------------
  // chunk c: tc = c>>12 (t-range [tc*32, tc*32+32)), r = c&4095 (skip r>=4032),
  //          nb = r>>6 (v-tile nb*128), b = r&63. Waves are independent.
  while (true) {
    unsigned c = 0;
    if (lane == 0) c = atomicAdd(bar + F_QCNT, 1u);
    c = __shfl(c, 0);
    if (c >= 16384u) break;
    unsigned tc = c >> 12, r = c & 4095u;
    if (r >= 4032u) continue;
    int nb = (int)(r >> 6), b = (int)(r & 63u);
    waitone<127>(bar + F_DRDY(tc));   // bseq[tc*32 .. tc*32+31] final

    const int n0 = nb * 128;
    f32x4 acc[2][8];
#pragma unroll
    for (int nt = 0; nt < 8; ++nt) {
      int v = n0 + nt * 16 + n;
      float bd = (v < NV) ? a.bdec[v] : 0.f;
      acc[0][nt] = (f32x4){bd, bd, bd, bd};
      acc[1][nt] = acc[0][nt];
    }
    const unsigned short* arow[2];
#pragma unroll
    for (int mt = 0; mt < 2; ++mt)
      arow[mt] = a.bseq + ((size_t)(tc * 32 + mt * 16 + n) * NBATCH + b) * NH;
    const unsigned short* brow[8];
#pragma unroll
    for (int nt = 0; nt < 8; ++nt) brow[nt] = a.wdec + (size_t)(n0 + nt * 16 + n) * NH;

#pragma unroll 4
    for (int s = 0; s < 16; ++s) {
      bf16x8 af[2];
#pragma unroll
      for (int mt = 0; mt < 2; ++mt) af[mt] = *(const bf16x8*)(arow[mt] + s * 32 + q * 8);
#pragma unroll
      for (int nt = 0; nt < 8; ++nt) {
        bf16x8 bf = *(const bf16x8*)(brow[nt] + s * 32 + q * 8);
#pragma unroll
        for (int mt = 0; mt < 2; ++mt)
          acc[mt][nt] = __builtin_amdgcn_mfma_f32_16x16x32_bf16(af[mt], bf, acc[mt][nt], 0, 0, 0);
      }
    }
#pragma unroll
    for (int mt = 0; mt < 2; ++mt)
#pragma unroll
      for (int nt = 0; nt < 8; ++nt) {
        int v = n0 + nt * 16 + n;
        if (v < NV) {
          int t0 = (int)tc * 32 + mt * 16 + q * 4;
          *(f32x4*)(a.out + ((size_t)b * NV + v) * NSTEP + t0) = acc[mt][nt];
        }
      }
  }
}

// ---------------- launch ----------------
extern "C" void kernel_launch(void* const* d_in, const int* in_sizes, int n_in,
                              void* d_out, int out_size, void* d_ws, size_t ws_size,
                              hipStream_t stream) {
  char* ws = (char*)d_ws;

  KArgs a;
  a.x    = (const int*)d_in[0];
  a.emb  = (const float*)d_in[1];
  a.Wih1 = (const float*)d_in[2];
  a.Whh1 = (const float*)d_in[3];
  a.bi1  = (const float*)d_in[4];
  a.bh1  = (const float*)d_in[5];
  a.g1   = (const float*)d_in[6];
  a.be1  = (const float*)d_in[7];
  a.m1   = (const float*)d_in[8];
  a.Wih2 = (const float*)d_in[9];
  a.Whh2 = (const float*)d_in[10];
  a.bi2  = (const float*)d_in[11];
  a.bh2  = (const float*)d_in[12];
  a.g2   = (const float*)d_in[13];
  a.be2  = (const float*)d_in[14];
  a.m2   = (const float*)d_in[15];
  a.Wdec = (const float*)d_in[16];
  a.bdec = (const float*)d_in[17];
  a.xs   = (unsigned short*)(ws + OFF_XS);
  a.wp   = (unsigned short*)(ws + OFF_WP);
  a.wdec = (unsigned short*)(ws + OFF_WDEC);
  a.bias = (float*)(ws + OFF_BIAS);
  a.h1q  = (unsigned short*)(ws + OFF_H1);
  a.abq  = (unsigned short*)(ws + OFF_AB);
  a.h2q  = (unsigned short*)(ws + OFF_H2);
  a.bseq = (unsigned short*)(ws + OFF_BSEQ);
  a.bar  = (unsigned*)(ws + OFF_BAR);
  a.out  = (float*)d_out;

  // zero all flags (ws is poisoned 0xAA before every call)
  (void)hipMemsetAsync(a.bar, 0, SZ_BAR, stream);

  void* kargs[] = {(void*)&a};
  (void)hipLaunchCooperativeKernel((void*)k_main, dim3(256), dim3(256), kargs, 0, stream);
}